// Round 5
// baseline (1304.984 us; speedup 1.0000x reference)
//
#include <hip/hip_runtime.h>
#include <stdint.h>
#include <stddef.h>

// ---------------------------------------------------------------------------
// Neural SDE: B=2048 paths, 64 Euler-Maruyama steps.
// R5: all-resident decomposition. 64 groups x 4 WGs (=256 WGs, 1/CU, forced
// by LDS>80KB). Each group owns 32 batch rows; each WG holds one h-quarter of
// Wc2 (64 VGPRs/wave) permanently in registers -- zero weight streaming in
// the step loop. Per step the 4 replicas exchange 1KB of bf16-packed per-h
// diffusion sums via d_ws (agent-scope atomics, parity double buffer,
// step-stamped flags zeroed by prep each launch). Replicas consume identical
// bf16-rounded deltas so y stays bit-exact across the quad.
// R4->R5 fixes: (1) publisher (wave0) and spinners (waves1-3) on DIFFERENT
// waves -- no intra-wave divergence deadlock; (2) ws footprint 1.81MB->763KB:
// delta overlays the dead Wc2-swizzle region behind an init grid barrier.
// ---------------------------------------------------------------------------

typedef __attribute__((ext_vector_type(8))) short bf16x8;   // 8 x bf16 (4 VGPR)
typedef __attribute__((ext_vector_type(4))) float f32x4;    // MFMA C/D
typedef __attribute__((ext_vector_type(4))) int   i32x4;    // 16B copies

// ---- ws layout (bytes), all bf16 fragment-swizzled weights --------------
#define WS_WI0 0        // 8 frags   (128x32  K=32  KI=1 NT=8)
#define WS_WI1 8192     // 32 frags  (128x128)
#define WS_WI2 40960    // 16 frags  (64x128)
#define WS_WV0 57344    // 16 frags  (128x64, t-col dropped)
#define WS_WV1 73728    // 32 frags
#define WS_WV2 106496   // 16 frags
#define WS_WC0 122880   // 16 frags
#define WS_WC1 139264   // 32 frags
#define WS_WC2 172032   // 512 frags (2048x128) = 512 KB (dead after init)
#define WS_TV0 696320   // Wv0[:,0] f32 [128]
#define WS_TC0 696832   // Wc0[:,0] f32 [128]
#define WS_FLAG 697344  // int [64 grp][4 q][64 step] = 64 KB (prep zeroes)
#define WS_CNT  762880  // int: init-barrier counter (prep zeroes)
// delta overlays Wc2 after the init barrier: u32[64 g][4 q][2 par][256]
#define WS_DELTA WS_WC2 // 64*4*2*256*4 = 512 KB, exact fit

// ---- LDS layout (bytes) --------------------------------------------------
#define LD_WV0 0        // 16384
#define LD_WV1 16384    // 32768
#define LD_WC0 49152    // 16384
#define LD_WC1 65536    // 32768
#define LD_YBF 98304    // 4096: y A-frags, 2 rg x K=64. DSUM f32[32][16] overlays.
#define LD_H1V 102400   // 8192 (DB f32[32][65]=8320 overlays H1V+H1C head)
#define LD_H1C 110592   // 8192
#define LD_H2V 118784   // 8192
#define LD_H2C 126976   // 8192
#define LD_Y   135168   // 8320: f32 [32][65]
#define LD_BM  143488   // 4224: f32 [32][33]
#define LD_BC2 147712   // 1024: bf16[512] quarter's bc2
#define LD_SCC 148736   // 1024: bf16[512] quarter's scale_c
#define LD_BEV 149760   // 512
#define LD_BEC 150272   // 512
#define LD_BV1 150784   // 512
#define LD_BC1 151296   // 512
#define LD_BV2 151808   // 256
#define LD_SV  152064   // 256
#define LD_WR  152320   // 2080: f32 [8][65]
#define LD_BR  154400   // 32
#define LDS_TOTAL 154432   // >80KB => exactly 1 WG/CU => 256 WGs all resident
#define LD_DSUM LD_YBF
#define LD_DB  LD_H1V

__device__ __forceinline__ short f2bf(float f) {
  uint32_t u = __builtin_bit_cast(uint32_t, f);
  uint32_t r = (u + 0x7fffu + ((u >> 16) & 1u)) >> 16;   // RNE
  return (short)r;
}
__device__ __forceinline__ float bf2f(short s) {
  uint32_t u = ((uint32_t)(uint16_t)s) << 16;
  return __builtin_bit_cast(float, u);
}
__device__ __forceinline__ float tanh_fast(float x) {
  x = fminf(15.f, fmaxf(-15.f, x));
  float e = __builtin_amdgcn_exp2f(x * 2.8853900817779268f); // 2*log2(e)
  return (e - 1.f) * __builtin_amdgcn_rcpf(e + 1.f);
}
__device__ __forceinline__ float lipswish(float x) {
  float s = __builtin_amdgcn_rcpf(1.f + __builtin_amdgcn_exp2f(-1.4426950408889634f * x));
  return 0.909f * x * s;
}
// sum over the 16 lanes of each DPP row group
__device__ __forceinline__ float red16(float x) {
  int v;
  v = __builtin_amdgcn_update_dpp(0, __builtin_bit_cast(int, x), 0xB1, 0xF, 0xF, true);
  x += __builtin_bit_cast(float, v);
  v = __builtin_amdgcn_update_dpp(0, __builtin_bit_cast(int, x), 0x4E, 0xF, 0xF, true);
  x += __builtin_bit_cast(float, v);
  v = __builtin_amdgcn_update_dpp(0, __builtin_bit_cast(int, x), 0x141, 0xF, 0xF, true);
  x += __builtin_bit_cast(float, v);
  v = __builtin_amdgcn_update_dpp(0, __builtin_bit_cast(int, x), 0x140, 0xF, 0xF, true);
  x += __builtin_bit_cast(float, v);
  return x;
}
// write activation element (m,k) into a fragment-swizzled bf16 A-buffer
__device__ __forceinline__ void write_act(char* buf, int m, int k, short v) {
  int addr = ((k >> 5) << 10) + (m + ((k >> 3) & 3) * 16) * 16 + ((k & 7) << 1);
  *(short*)(buf + addr) = v;
}

template<int KF>
__device__ __forceinline__ f32x4 gemm_tile(const char* abase, const char* bbase, int lane) {
  f32x4 acc = {0.f, 0.f, 0.f, 0.f};
#pragma unroll
  for (int k = 0; k < KF; k++) {
    bf16x8 a = *(const bf16x8*)(abase + k * 1024 + lane * 16);
    bf16x8 b = *(const bf16x8*)(bbase + k * 1024 + lane * 16);
    acc = __builtin_amdgcn_mfma_f32_16x16x32_bf16(a, b, acc, 0, 0, 0);
  }
  return acc;
}

// ---------------------------------------------------------------------------
// Prep: convert f32 weights -> bf16 fragment-swizzled blobs in ws; zero the
// exchange flags + init counter (runs before sde_kernel on the same stream).
// ---------------------------------------------------------------------------
__global__ __launch_bounds__(256) void prep_kernel(
    const float* Wi0, const float* Wi1, const float* Wi2,
    const float* Wv0, const float* Wv1, const float* Wv2,
    const float* Wc0, const float* Wc1, const float* Wc2, char* ws) {
  int gid = blockIdx.x * 256 + threadIdx.x;
  if (gid < 680 * 64) {
    int frag = gid >> 6, lane = gid & 63;
    const float* src; int start, KI, srcK, c0;
    if      (frag < 8)   { src = Wi0; start = 0;   KI = 1; srcK = 32;  c0 = 0; }
    else if (frag < 40)  { src = Wi1; start = 8;   KI = 4; srcK = 128; c0 = 0; }
    else if (frag < 56)  { src = Wi2; start = 40;  KI = 4; srcK = 128; c0 = 0; }
    else if (frag < 72)  { src = Wv0; start = 56;  KI = 2; srcK = 65;  c0 = 1; }
    else if (frag < 104) { src = Wv1; start = 72;  KI = 4; srcK = 128; c0 = 0; }
    else if (frag < 120) { src = Wv2; start = 104; KI = 4; srcK = 128; c0 = 0; }
    else if (frag < 136) { src = Wc0; start = 120; KI = 2; srcK = 65;  c0 = 1; }
    else if (frag < 168) { src = Wc1; start = 136; KI = 4; srcK = 128; c0 = 0; }
    else                 { src = Wc2; start = 168; KI = 4; srcK = 128; c0 = 0; }
    int rel = frag - start;
    int nt = rel / KI, ki = rel % KI;
    int n16 = lane & 15, quad = lane >> 4;
    const float* s = src + (nt * 16 + n16) * srcK + c0 + ki * 32 + quad * 8;
    bf16x8 v;
#pragma unroll
    for (int j = 0; j < 8; j++) v[j] = f2bf(s[j]);
    *(bf16x8*)(ws + (size_t)frag * 1024 + lane * 16) = v;
  } else if (gid < 680 * 64 + 256) {
    int i = gid - 680 * 64;
    if (i < 128)      ((float*)(ws + WS_TV0))[i] = Wv0[i * 65];
    else              ((float*)(ws + WS_TC0))[i - 128] = Wc0[(i - 128) * 65];
  } else {
    int i = gid - (680 * 64 + 256);
    if (i < 16384)      ((int*)(ws + WS_FLAG))[i] = 0;
    else if (i == 16384) ((int*)(ws + WS_CNT))[0] = 0;
  }
}

// ---------------------------------------------------------------------------
// Main kernel: 256 WGs = 64 groups x 4 quarters. Group g owns rows g*32..+32.
// Quarter q owns Wc2 cols [q*512, q*512+512) (h in [q*16, q*16+16)).
// ---------------------------------------------------------------------------
__global__ __launch_bounds__(512, 2) void sde_kernel(
    const float* ts, const float* init_noise, const float* bm,
    const float* bi0, const float* bi1, const float* bi2,
    const float* bv0, const float* bv1, const float* bv2, const float* scale_v,
    const float* bc0, const float* bc1, const float* bc2, const float* scale_c,
    const float* Wr, const float* br,
    char* ws, float* out) {
  extern __shared__ __align__(16) char lds[];
  const int tid  = threadIdx.x;
  const int lane = tid & 63;
  const int wv   = tid >> 6;     // wave 0..7
  const int nl   = lane & 15;
  const int quad = lane >> 4;
  const int g    = blockIdx.x & 63;   // group: members bid = g + 64*q -> same XCD mod 8
  const int q    = blockIdx.x >> 6;   // quarter 0..3
  const int b0   = g * 32;

  uint32_t* delta = (uint32_t*)(ws + WS_DELTA);
  int*      flags = (int*)(ws + WS_FLAG);

  // ---- Wc2 quarter into VGPRs: wave wv holds col-tiles nt = q*32+wv*4+j ----
  bf16x8 wf[4][4];
#pragma unroll
  for (int j = 0; j < 4; j++) {
    int nt = q * 32 + wv * 4 + j;
#pragma unroll
    for (int k = 0; k < 4; k++)
      wf[j][k] = *(const bf16x8*)(ws + WS_WC2 + (size_t)(nt * 4 + k) * 1024 + lane * 16);
  }
  // ---- drift L3 weights (waves 0-3) into VGPRs ----
  bf16x8 vf[4] = {};
  if (wv < 4) {
#pragma unroll
    for (int k = 0; k < 4; k++)
      vf[k] = *(const bf16x8*)(ws + WS_WV2 + wv * 4096 + k * 1024 + lane * 16);
  }

  // ---- stage small weights & params into LDS ----
  {
    const i32x4* s0 = (const i32x4*)(ws + WS_WV0);   // WV0+WV1 = 49152 B
    const i32x4* s1 = (const i32x4*)(ws + WS_WC0);   // WC0+WC1 = 49152 B
    i32x4* d0 = (i32x4*)(lds + LD_WV0);
    i32x4* d1 = (i32x4*)(lds + LD_WC0);
    for (int j = tid; j < 3072; j += 512) { d0[j] = s0[j]; d1[j] = s1[j]; }
  }
  { // quarter's bc2 / scale_c (flat idx == col)
    ((short*)(lds + LD_BC2))[tid] = f2bf(bc2[q * 512 + tid]);      // tid<512
    ((short*)(lds + LD_SCC))[tid] = f2bf(scale_c[q * 512 + tid]);
  }
  if (tid < 128)      { ((float*)(lds + LD_BV1))[tid] = bv1[tid];
                        ((float*)(lds + LD_BC1))[tid] = bc1[tid]; }
  else if (tid < 192) { int k = tid - 128; ((float*)(lds + LD_BV2))[k] = bv2[k];
                        ((float*)(lds + LD_SV))[k] = scale_v[k]; }
  else if (tid < 200) { int k = tid - 192; ((float*)(lds + LD_BR))[k] = br[k]; }
  { int dd = tid >> 6, k = tid & 63;
    ((float*)(lds + LD_WR))[dd * 65 + k] = Wr[dd * 64 + k]; }
  // init noise -> YBF (K=32), 2 row groups
  for (int e = tid; e < 1024; e += 512) {
    int m = e >> 5, k = e & 31;
    write_act(lds + LD_YBF + (m >> 4) * 2048, m & 15, k, f2bf(init_noise[(b0 + m) * 32 + k]));
  }
  __syncthreads();   // also drains every wave's Wc2 register loads (vmcnt 0)

  // ---- init grid barrier: delta may not overlay Wc2 until ALL WGs read it.
  // Publisher (wave0 lane0) and spinner (wave1 lane0) are different waves.
  {
    int* cnt = (int*)(ws + WS_CNT);
    if (tid == 0)
      __hip_atomic_fetch_add(cnt, 1, __ATOMIC_RELAXED, __HIP_MEMORY_SCOPE_AGENT);
    if (tid == 64) {
      while (__hip_atomic_load(cnt, __ATOMIC_RELAXED, __HIP_MEMORY_SCOPE_AGENT) != 256)
        __builtin_amdgcn_s_sleep(8);
    }
    __syncthreads();
  }

  // ---- init MLP ----
#pragma unroll
  for (int rg = 0; rg < 2; rg++) { // L1i relu
    f32x4 acc = gemm_tile<1>(lds + LD_YBF + rg * 2048, ws + WS_WI0 + wv * 1024, lane);
    int col = wv * 16 + nl; float bias = bi0[col];
#pragma unroll
    for (int r = 0; r < 4; r++)
      write_act(lds + LD_H1V + rg * 4096, quad * 4 + r, col, f2bf(fmaxf(0.f, acc[r] + bias)));
  }
  __syncthreads();
#pragma unroll
  for (int rg = 0; rg < 2; rg++) { // L2i relu
    f32x4 acc = gemm_tile<4>(lds + LD_H1V + rg * 4096, ws + WS_WI1 + wv * 4096, lane);
    int col = wv * 16 + nl; float bias = bi1[col];
#pragma unroll
    for (int r = 0; r < 4; r++)
      write_act(lds + LD_H2V + rg * 4096, quad * 4 + r, col, f2bf(fmaxf(0.f, acc[r] + bias)));
  }
  __syncthreads();
  if (wv < 4) { // L3i identity -> Y
#pragma unroll
    for (int rg = 0; rg < 2; rg++) {
      f32x4 acc = gemm_tile<4>(lds + LD_H2V + rg * 4096, ws + WS_WI2 + wv * 4096, lane);
      int col = wv * 16 + nl; float bias = bi2[col];
#pragma unroll
      for (int r = 0; r < 4; r++)
        ((float*)(lds + LD_Y))[(rg * 16 + quad * 4 + r) * 65 + col] = acc[r] + bias;
    }
  }
  __syncthreads();

  // ---- preamble: YBF from Y (K=64), bm step0, effective biases step0 ----
  const float ts0 = ts[0];
  for (int e = tid; e < 2048; e += 512) {
    int row = e >> 6, k = e & 63;
    write_act(lds + LD_YBF + (row >> 4) * 2048, row & 15, k,
              f2bf(((float*)(lds + LD_Y))[row * 65 + k]));
  }
  for (int e = tid; e < 1024; e += 512) {
    int row = e >> 5, n = e & 31;
    ((float*)(lds + LD_BM))[row * 33 + n] = bm[((size_t)(b0 + row) * 64 + 0) * 32 + n];
  }
  if (tid < 128)
    ((float*)(lds + LD_BEV))[tid] = bv0[tid] + ts0 * ((const float*)(ws + WS_TV0))[tid];
  else if (tid < 256) { int k = tid - 128;
    ((float*)(lds + LD_BEC))[k] = bc0[k] + ts0 * ((const float*)(ws + WS_TC0))[k]; }
  __syncthreads();

  // ================= 64-step scan =================
  for (int step = 0; step < 64; step++) {
    const int par = step & 1;
    // ---- L1 ----
    {
      int col = wv * 16 + nl;
      float bv = ((float*)(lds + LD_BEV))[col];
      float bc = ((float*)(lds + LD_BEC))[col];
#pragma unroll
      for (int rg = 0; rg < 2; rg++) {
        f32x4 av = gemm_tile<2>(lds + LD_YBF + rg * 2048, lds + LD_WV0 + wv * 2048, lane);
        f32x4 ac = gemm_tile<2>(lds + LD_YBF + rg * 2048, lds + LD_WC0 + wv * 2048, lane);
#pragma unroll
        for (int r = 0; r < 4; r++) {
          write_act(lds + LD_H1V + rg * 4096, quad * 4 + r, col, f2bf(lipswish(av[r] + bv)));
          write_act(lds + LD_H1C + rg * 4096, quad * 4 + r, col, f2bf(lipswish(ac[r] + bc)));
        }
      }
    }
    __syncthreads();   // B1
    // ---- L2 ----
    {
      int col = wv * 16 + nl;
      float bv = ((float*)(lds + LD_BV1))[col];
      float bc = ((float*)(lds + LD_BC1))[col];
#pragma unroll
      for (int rg = 0; rg < 2; rg++) {
        f32x4 av = gemm_tile<4>(lds + LD_H1V + rg * 4096, lds + LD_WV1 + wv * 4096, lane);
        f32x4 ac = gemm_tile<4>(lds + LD_H1C + rg * 4096, lds + LD_WC1 + wv * 4096, lane);
#pragma unroll
        for (int r = 0; r < 4; r++) {
          write_act(lds + LD_H2V + rg * 4096, quad * 4 + r, col, f2bf(lipswish(av[r] + bv)));
          write_act(lds + LD_H2C + rg * 4096, quad * 4 + r, col, f2bf(lipswish(ac[r] + bc)));
        }
      }
    }
    __syncthreads();   // B2
    // ---- L3: drift (waves 0-3) writes DB; all waves: Wc2 quarter -> DSUM ----
    if (wv < 4) {
      int col = wv * 16 + nl;
      float bias = ((float*)(lds + LD_BV2))[col];
      float sv   = ((float*)(lds + LD_SV))[col];
#pragma unroll
      for (int rg = 0; rg < 2; rg++) {
        f32x4 acc = {0.f, 0.f, 0.f, 0.f};
#pragma unroll
        for (int k = 0; k < 4; k++) {
          bf16x8 a = *(const bf16x8*)(lds + LD_H2V + rg * 4096 + k * 1024 + lane * 16);
          acc = __builtin_amdgcn_mfma_f32_16x16x32_bf16(a, vf[k], acc, 0, 0, 0);
        }
#pragma unroll
        for (int r = 0; r < 4; r++)
          ((float*)(lds + LD_DB))[(rg * 16 + quad * 4 + r) * 65 + col] =
              sv * tanh_fast(acc[r] + bias);
      }
    }
#pragma unroll
    for (int rg = 0; rg < 2; rg++) {
      bf16x8 a[4];
#pragma unroll
      for (int k = 0; k < 4; k++)
        a[k] = *(const bf16x8*)(lds + LD_H2C + rg * 4096 + k * 1024 + lane * 16);
      float bmr0[4], bmr1[4];
#pragma unroll
      for (int r = 0; r < 4; r++) {
        int row = rg * 16 + quad * 4 + r;
        bmr0[r] = ((float*)(lds + LD_BM))[row * 33 + nl];
        bmr1[r] = ((float*)(lds + LD_BM))[row * 33 + 16 + nl];
      }
      float ps[4] = {0.f, 0.f, 0.f, 0.f};
#pragma unroll
      for (int j = 0; j < 4; j++) {
        f32x4 acc = {0.f, 0.f, 0.f, 0.f};
#pragma unroll
        for (int k = 0; k < 4; k++)
          acc = __builtin_amdgcn_mfma_f32_16x16x32_bf16(a[k], wf[j][k], acc, 0, 0, 0);
        int cl = (wv * 4 + j) * 16 + nl;   // col within quarter
        float bc2v = bf2f(((short*)(lds + LD_BC2))[cl]);
        float scv  = bf2f(((short*)(lds + LD_SCC))[cl]);
        int half = j & 1;
#pragma unroll
        for (int r = 0; r < 4; r++) {
          float bmv = half ? bmr1[r] : bmr0[r];
          float p = tanh_fast(acc[r] + bc2v) * scv * bmv;
          ps[r] = half ? (ps[r] + p) : p;
        }
        if (half) {
#pragma unroll
          for (int r = 0; r < 4; r++) ps[r] = red16(ps[r]);
          if (nl < 4) {
            int row = rg * 16 + quad * 4 + nl;
            int hl  = wv * 2 + (j >> 1);   // h-local 0..15
            float s = (nl == 0) ? ps[0] : (nl == 1) ? ps[1] : (nl == 2) ? ps[2] : ps[3];
            ((float*)(lds + LD_DSUM))[row * 16 + hl] = s;
          }
        }
      }
    }
    __syncthreads();   // B3: DSUM complete in LDS
    // ---- publish quarter's delta (bf16 pairs packed in u32) ----
    if (tid < 256) {
      const float* ds = (const float*)(lds + LD_DSUM);
      uint32_t u = (uint32_t)(uint16_t)f2bf(ds[2 * tid]) |
                   ((uint32_t)(uint16_t)f2bf(ds[2 * tid + 1]) << 16);
      __hip_atomic_store(&delta[((g * 4 + q) * 2 + par) * 256 + tid], u,
                         __ATOMIC_RELAXED, __HIP_MEMORY_SCOPE_AGENT);
    }
    __syncthreads();   // B3b: all waves' delta stores drained (vmcnt0 pre-barrier)
    if (tid == 0)      // publisher: wave 0
      __hip_atomic_store(&flags[(g * 4 + q) * 64 + step], step + 1,
                         __ATOMIC_RELEASE, __HIP_MEMORY_SCOPE_AGENT);
    if (tid == 64 || tid == 128 || tid == 192) {   // spinners: waves 1-3
      int qq = (q + (tid >> 6)) & 3;
      int fidx = (g * 4 + qq) * 64 + step;
      while (__hip_atomic_load(&flags[fidx], __ATOMIC_ACQUIRE,
                               __HIP_MEMORY_SCOPE_AGENT) != step + 1)
        __builtin_amdgcn_s_sleep(2);
    }
    __syncthreads();   // B4: all partner deltas visible
    // ---- M: v = y + drift + delta(h); stage next bm & biases ----
    float vnew[4];
    {
      int row = tid >> 4, kb = (tid & 15) * 4;
      int qh = kb >> 4, l = kb & 15;
      const float* Yp  = (const float*)(lds + LD_Y)  + row * 65 + kb;
      const float* DBp = (const float*)(lds + LD_DB) + row * 65 + kb;
      float dv[4];
      if (qh == q) {   // own quarter: identical bf16 round-trip
        const float* ds = (const float*)(lds + LD_DSUM);
#pragma unroll
        for (int jj = 0; jj < 4; jj++) dv[jj] = bf2f(f2bf(ds[row * 16 + l + jj]));
      } else {
        int base = ((g * 4 + qh) * 2 + par) * 256 + ((row * 16 + l) >> 1);
#pragma unroll
        for (int p2 = 0; p2 < 2; p2++) {
          uint32_t u = __hip_atomic_load(&delta[base + p2], __ATOMIC_RELAXED,
                                         __HIP_MEMORY_SCOPE_AGENT);
          dv[2 * p2]     = bf2f((short)(u & 0xffffu));
          dv[2 * p2 + 1] = bf2f((short)(u >> 16));
        }
      }
#pragma unroll
      for (int jj = 0; jj < 4; jj++) vnew[jj] = Yp[jj] + DBp[jj] + dv[jj];
    }
    if (step + 1 < 64) {
      for (int e = tid; e < 1024; e += 512) {
        int row = e >> 5, n = e & 31;
        ((float*)(lds + LD_BM))[row * 33 + n] =
            bm[((size_t)(b0 + row) * 64 + (step + 1)) * 32 + n];
      }
      float tnext = ts0 + (float)(step + 1);
      if (tid < 128)
        ((float*)(lds + LD_BEV))[tid] = bv0[tid] + tnext * ((const float*)(ws + WS_TV0))[tid];
      else if (tid < 256) { int k = tid - 128;
        ((float*)(lds + LD_BEC))[k] = bc0[k] + tnext * ((const float*)(ws + WS_TC0))[k]; }
    }
    __syncthreads();   // B5: DSUM fully consumed; now overwrite Y/YBF
    {
      int row = tid >> 4, kb = (tid & 15) * 4;
      float* Yp = (float*)(lds + LD_Y) + row * 65 + kb;
      char* yb = lds + LD_YBF + (row >> 4) * 2048;
#pragma unroll
      for (int jj = 0; jj < 4; jj++) {
        Yp[jj] = vnew[jj];
        write_act(yb, row & 15, kb + jj, f2bf(vnew[jj]));
      }
    }
    __syncthreads();   // B6: Y/YBF ready
    // ---- readout: this quarter handles rows [q*8, q*8+8) ----
    if (tid < 64) {
      int r8 = tid >> 3, dd = tid & 7;
      int row = q * 8 + r8;
      const float* yr = (const float*)(lds + LD_Y) + row * 65;
      const float* wr = (const float*)(lds + LD_WR) + dd * 65;
      float s = ((float*)(lds + LD_BR))[dd];
#pragma unroll
      for (int k = 0; k < 64; k++) s = fmaf(yr[k], wr[k], s);
      out[(size_t)(b0 + row) * 512 + step * 8 + dd] = s;
    }
  }
}

extern "C" void kernel_launch(void* const* d_in, const int* in_sizes, int n_in,
                              void* d_out, int out_size, void* d_ws, size_t ws_size,
                              hipStream_t stream) {
  (void)in_sizes; (void)n_in; (void)out_size; (void)ws_size;
  const float* ts         = (const float*)d_in[0];
  const float* init_noise = (const float*)d_in[1];
  const float* bm         = (const float*)d_in[2];
  const float* Wi0 = (const float*)d_in[3];
  const float* bi0 = (const float*)d_in[4];
  const float* Wi1 = (const float*)d_in[5];
  const float* bi1 = (const float*)d_in[6];
  const float* Wi2 = (const float*)d_in[7];
  const float* bi2 = (const float*)d_in[8];
  const float* scale_v = (const float*)d_in[9];
  const float* Wv0 = (const float*)d_in[10];
  const float* bv0 = (const float*)d_in[11];
  const float* Wv1 = (const float*)d_in[12];
  const float* bv1 = (const float*)d_in[13];
  const float* Wv2 = (const float*)d_in[14];
  const float* bv2 = (const float*)d_in[15];
  const float* scale_c = (const float*)d_in[16];
  const float* Wc0 = (const float*)d_in[17];
  const float* bc0 = (const float*)d_in[18];
  const float* Wc1 = (const float*)d_in[19];
  const float* bc1 = (const float*)d_in[20];
  const float* Wc2 = (const float*)d_in[21];
  const float* bc2 = (const float*)d_in[22];
  const float* Wr  = (const float*)d_in[23];
  const float* br  = (const float*)d_in[24];
  char*  ws  = (char*)d_ws;
  float* out = (float*)d_out;

  hipFuncSetAttribute((const void*)sde_kernel,
                      hipFuncAttributeMaxDynamicSharedMemorySize, LDS_TOTAL);

  prep_kernel<<<236, 256, 0, stream>>>(Wi0, Wi1, Wi2, Wv0, Wv1, Wv2, Wc0, Wc1, Wc2, ws);
  sde_kernel<<<256, 512, LDS_TOTAL, stream>>>(
      ts, init_noise, bm, bi0, bi1, bi2, bv0, bv1, bv2, scale_v,
      bc0, bc1, bc2, scale_c, Wr, br, ws, out);
}

// Round 6
// 582.873 us; speedup vs baseline: 2.2389x; 2.2389x over previous
//
#include <hip/hip_runtime.h>
#include <stdint.h>
#include <stddef.h>

// ---------------------------------------------------------------------------
// Neural SDE: B=2048 paths, 64 Euler-Maruyama steps.
// R6: self-contained 128 WGs x 512 thr, BB=16 rows/WG (R1 structure; R5's
// cross-WG exchange measured ~12us/step -- abandoned). Stall fixes:
//  - 4/16 Wc2 tiles register-resident (wf), 12 streamed via depth-4 ring
//    with fills issued at STEP TOP (2us of L1/L2 compute hides L2 latency)
//  - bm prefetched to regs at step top; BEV/BEC from persistent regs
//    (no global loads drain inside the M barrier)
//  - packed (bc2|scc) ds_read_b32; Wv2 in regs; Y/DB stride 68 -> b128 M
// ---------------------------------------------------------------------------

typedef __attribute__((ext_vector_type(8))) short bf16x8;   // 8 x bf16 (4 VGPR)
typedef __attribute__((ext_vector_type(4))) float f32x4;    // MFMA C/D
typedef __attribute__((ext_vector_type(4))) int   i32x4;    // 16B copies

#define BB 16
#define NWG 128

// ---- ws layout (bytes), all bf16 fragment-swizzled weights --------------
#define WS_WI0 0        // 8 frags   (128x32  K=32  KI=1 NT=8)
#define WS_WI1 8192     // 32 frags  (128x128)
#define WS_WI2 40960    // 16 frags  (64x128)
#define WS_WV0 57344    // 16 frags  (128x64, t-col dropped)
#define WS_WV1 73728    // 32 frags
#define WS_WV2 106496   // 16 frags
#define WS_WC0 122880   // 16 frags
#define WS_WC1 139264   // 32 frags
#define WS_WC2 172032   // 512 frags (2048x128) = 512 KB
#define WS_TV0 696320   // Wv0[:,0] f32 [128]
#define WS_TC0 696832   // Wc0[:,0] f32 [128]

// ---- LDS layout (bytes) --------------------------------------------------
#define LD_WV0 0        // 16384
#define LD_WV1 16384    // 32768
#define LD_WC0 49152    // 16384
#define LD_WC1 65536    // 32768
#define LD_YBF 98304    // 2048: y A-frags K=64
#define LD_H1V 100352   // 4096
#define LD_H1C 104448   // 4096
#define LD_H2V 108544   // 4096
#define LD_H2C 112640   // 4096
#define LD_Y   116736   // f32 [16][68] = 4352 (stride 68: 16B-aligned rows)
#define LD_DB  121088   // f32 [16][68]
#define LD_BM  125440   // f32 [16][33] = 2112
#define LD_BSC 127552   // u32 [2048]: bc2(bf16) | scale_c(bf16)<<16 per col
#define LD_BEV 135744   // f32 [128]
#define LD_BEC 136256
#define LD_BV1 136768
#define LD_BC1 137280
#define LD_BV2 137792   // f32 [64]
#define LD_SV  138048
#define LD_WR  138304   // f32 [8][68] = 2176
#define LD_BR  140480   // 32
#define LDS_TOTAL 140512   // >80KB => 1 WG/CU

__device__ __forceinline__ short f2bf(float f) {
  uint32_t u = __builtin_bit_cast(uint32_t, f);
  uint32_t r = (u + 0x7fffu + ((u >> 16) & 1u)) >> 16;   // RNE
  return (short)r;
}
__device__ __forceinline__ float bf2f(short s) {
  uint32_t u = ((uint32_t)(uint16_t)s) << 16;
  return __builtin_bit_cast(float, u);
}
__device__ __forceinline__ float tanh_fast(float x) {
  x = fminf(15.f, fmaxf(-15.f, x));
  float e = __builtin_amdgcn_exp2f(x * 2.8853900817779268f);
  return (e - 1.f) * __builtin_amdgcn_rcpf(e + 1.f);
}
__device__ __forceinline__ float lipswish(float x) {
  float s = __builtin_amdgcn_rcpf(1.f + __builtin_amdgcn_exp2f(-1.4426950408889634f * x));
  return 0.909f * x * s;
}
__device__ __forceinline__ float red16(float x) {
  int v;
  v = __builtin_amdgcn_update_dpp(0, __builtin_bit_cast(int, x), 0xB1, 0xF, 0xF, true);
  x += __builtin_bit_cast(float, v);
  v = __builtin_amdgcn_update_dpp(0, __builtin_bit_cast(int, x), 0x4E, 0xF, 0xF, true);
  x += __builtin_bit_cast(float, v);
  v = __builtin_amdgcn_update_dpp(0, __builtin_bit_cast(int, x), 0x141, 0xF, 0xF, true);
  x += __builtin_bit_cast(float, v);
  v = __builtin_amdgcn_update_dpp(0, __builtin_bit_cast(int, x), 0x140, 0xF, 0xF, true);
  x += __builtin_bit_cast(float, v);
  return x;
}
// write activation element (m,k) into a fragment-swizzled bf16 A-buffer
__device__ __forceinline__ void write_act(char* buf, int m, int k, short v) {
  int addr = ((k >> 5) << 10) + (m + ((k >> 3) & 3) * 16) * 16 + ((k & 7) << 1);
  *(short*)(buf + addr) = v;
}

template<int KF>
__device__ __forceinline__ f32x4 gemm_tile(const char* abase, const char* bbase, int lane) {
  f32x4 acc = {0.f, 0.f, 0.f, 0.f};
#pragma unroll
  for (int k = 0; k < KF; k++) {
    bf16x8 a = *(const bf16x8*)(abase + k * 1024 + lane * 16);
    bf16x8 b = *(const bf16x8*)(bbase + k * 1024 + lane * 16);
    acc = __builtin_amdgcn_mfma_f32_16x16x32_bf16(a, b, acc, 0, 0, 0);
  }
  return acc;
}

// ---------------------------------------------------------------------------
// Prep: f32 weights -> bf16 fragment-swizzled blobs in ws. (unchanged)
// ---------------------------------------------------------------------------
__global__ __launch_bounds__(256) void prep_kernel(
    const float* Wi0, const float* Wi1, const float* Wi2,
    const float* Wv0, const float* Wv1, const float* Wv2,
    const float* Wc0, const float* Wc1, const float* Wc2, char* ws) {
  int gid = blockIdx.x * 256 + threadIdx.x;
  if (gid < 680 * 64) {
    int frag = gid >> 6, lane = gid & 63;
    const float* src; int start, KI, srcK, c0;
    if      (frag < 8)   { src = Wi0; start = 0;   KI = 1; srcK = 32;  c0 = 0; }
    else if (frag < 40)  { src = Wi1; start = 8;   KI = 4; srcK = 128; c0 = 0; }
    else if (frag < 56)  { src = Wi2; start = 40;  KI = 4; srcK = 128; c0 = 0; }
    else if (frag < 72)  { src = Wv0; start = 56;  KI = 2; srcK = 65;  c0 = 1; }
    else if (frag < 104) { src = Wv1; start = 72;  KI = 4; srcK = 128; c0 = 0; }
    else if (frag < 120) { src = Wv2; start = 104; KI = 4; srcK = 128; c0 = 0; }
    else if (frag < 136) { src = Wc0; start = 120; KI = 2; srcK = 65;  c0 = 1; }
    else if (frag < 168) { src = Wc1; start = 136; KI = 4; srcK = 128; c0 = 0; }
    else                 { src = Wc2; start = 168; KI = 4; srcK = 128; c0 = 0; }
    int rel = frag - start;
    int nt = rel / KI, ki = rel % KI;
    int n16 = lane & 15, quad = lane >> 4;
    const float* s = src + (nt * 16 + n16) * srcK + c0 + ki * 32 + quad * 8;
    bf16x8 v;
#pragma unroll
    for (int j = 0; j < 8; j++) v[j] = f2bf(s[j]);
    *(bf16x8*)(ws + (size_t)frag * 1024 + lane * 16) = v;
  } else {
    int i = gid - 680 * 64;
    if (i < 128)      ((float*)(ws + WS_TV0))[i] = Wv0[i * 65];
    else if (i < 256) ((float*)(ws + WS_TC0))[i - 128] = Wc0[(i - 128) * 65];
  }
}

// ---------------------------------------------------------------------------
// Main persistent kernel: one WG = 16 batch rows, all 64 steps.
// ---------------------------------------------------------------------------
__global__ __launch_bounds__(512, 2) void sde_kernel(
    const float* ts, const float* init_noise, const float* bm,
    const float* bi0, const float* bi1, const float* bi2,
    const float* bv0, const float* bv1, const float* bv2, const float* scale_v,
    const float* bc0, const float* bc1, const float* bc2, const float* scale_c,
    const float* Wr, const float* br,
    const char* ws, float* out) {
  extern __shared__ __align__(16) char lds[];
  const int tid  = threadIdx.x;
  const int lane = tid & 63;
  const int wv   = tid >> 6;     // wave 0..7
  const int nl   = lane & 15;
  const int quad = lane >> 4;
  const int b0   = blockIdx.x * BB;
  const char* wc2 = ws + WS_WC2 + (size_t)(wv * 16) * 4096;  // this wave's 16 tiles

  // ---- resident Wc2 tiles 0..3 of this wave's slice (64 VGPRs) ----
  bf16x8 wf[4][4];
#pragma unroll
  for (int j = 0; j < 4; j++)
#pragma unroll
    for (int k = 0; k < 4; k++)
      wf[j][k] = *(const bf16x8*)(wc2 + j * 4096 + k * 1024 + lane * 16);
  // ---- drift L3 weights in regs (waves 0-3) ----
  bf16x8 vf[4] = {};
  if (wv < 4) {
#pragma unroll
    for (int k = 0; k < 4; k++)
      vf[k] = *(const bf16x8*)(ws + WS_WV2 + wv * 4096 + k * 1024 + lane * 16);
  }
  // ---- persistent per-thread effective-bias source regs (tid>=256) ----
  float tvq = 0.f, bbq = 0.f;
  if (tid >= 256) {
    int j = tid - 256;
    if (j < 128) { tvq = ((const float*)(ws + WS_TV0))[j];       bbq = bv0[j]; }
    else         { tvq = ((const float*)(ws + WS_TC0))[j - 128]; bbq = bc0[j - 128]; }
  }

  // ---- stage small weights & params into LDS ----
  {
    const i32x4* s0 = (const i32x4*)(ws + WS_WV0);   // WV0+WV1 = 49152 B
    const i32x4* s1 = (const i32x4*)(ws + WS_WC0);   // WC0+WC1 = 49152 B
    i32x4* d0 = (i32x4*)(lds + LD_WV0);
    i32x4* d1 = (i32x4*)(lds + LD_WC0);
    for (int j = tid; j < 3072; j += 512) { d0[j] = s0[j]; d1[j] = s1[j]; }
  }
  for (int j = tid; j < 2048; j += 512) {   // packed bc2|scale_c per col
    uint32_t u = (uint32_t)(uint16_t)f2bf(bc2[j]) |
                 ((uint32_t)(uint16_t)f2bf(scale_c[j]) << 16);
    ((uint32_t*)(lds + LD_BSC))[j] = u;
  }
  if (tid < 128)      { ((float*)(lds + LD_BV1))[tid] = bv1[tid];
                        ((float*)(lds + LD_BC1))[tid] = bc1[tid]; }
  else if (tid < 192) { int k = tid - 128; ((float*)(lds + LD_BV2))[k] = bv2[k];
                        ((float*)(lds + LD_SV))[k] = scale_v[k]; }
  else if (tid < 200) { int k = tid - 192; ((float*)(lds + LD_BR))[k] = br[k]; }
  { int dd = tid >> 6, k = tid & 63;
    ((float*)(lds + LD_WR))[dd * 68 + k] = Wr[dd * 64 + k]; }
  // init noise -> YBF (K=32)
  { int m = tid >> 5, k = tid & 31;
    write_act(lds + LD_YBF, m, k, f2bf(init_noise[(b0 + m) * 32 + k])); }
  __syncthreads();

  // ---- init MLP: noise -> y0 ----
  { f32x4 acc = gemm_tile<1>(lds + LD_YBF, ws + WS_WI0 + wv * 1024, lane);
    int col = wv * 16 + nl; float bias = bi0[col];
#pragma unroll
    for (int r = 0; r < 4; r++)
      write_act(lds + LD_H1V, quad * 4 + r, col, f2bf(fmaxf(0.f, acc[r] + bias))); }
  __syncthreads();
  { f32x4 acc = gemm_tile<4>(lds + LD_H1V, ws + WS_WI1 + wv * 4096, lane);
    int col = wv * 16 + nl; float bias = bi1[col];
#pragma unroll
    for (int r = 0; r < 4; r++)
      write_act(lds + LD_H2V, quad * 4 + r, col, f2bf(fmaxf(0.f, acc[r] + bias))); }
  __syncthreads();
  if (wv < 4) {
    f32x4 acc = gemm_tile<4>(lds + LD_H2V, ws + WS_WI2 + wv * 4096, lane);
    int col = wv * 16 + nl; float bias = bi2[col];
#pragma unroll
    for (int r = 0; r < 4; r++)
      ((float*)(lds + LD_Y))[(quad * 4 + r) * 68 + col] = acc[r] + bias;
  }
  __syncthreads();

  // ---- preamble: YBF from Y; bm step0; effective biases step0 ----
  const float ts0 = ts[0];
  for (int e = tid; e < 1024; e += 512) {
    int row = e >> 6, k = e & 63;
    write_act(lds + LD_YBF, row, k, f2bf(((float*)(lds + LD_Y))[row * 68 + k]));
  }
  ((float*)(lds + LD_BM))[(tid >> 5) * 33 + (tid & 31)] =
      bm[((size_t)(b0 + (tid >> 5)) * 64 + 0) * 32 + (tid & 31)];
  if (tid >= 256) {
    int j = tid - 256; float v = bbq + ts0 * tvq;
    if (j < 128) ((float*)(lds + LD_BEV))[j] = v;
    else         ((float*)(lds + LD_BEC))[j - 128] = v;
  }
  __syncthreads();

  // ================= 64-step scan =================
  for (int step = 0; step < 64; step++) {
    // ---- step-top prefetch: next bm to regs; ring fills tiles 4..7 ----
    float bm_next = 0.f;
    if (step + 1 < 64)
      bm_next = bm[((size_t)(b0 + (tid >> 5)) * 64 + (step + 1)) * 32 + (tid & 31)];
    bf16x8 rng[4][4];
#pragma unroll
    for (int p = 0; p < 4; p++)
#pragma unroll
      for (int k = 0; k < 4; k++)
        rng[p][k] = *(const bf16x8*)(wc2 + (4 + p) * 4096 + k * 1024 + lane * 16);

    // ---- L1 (shared A-frags for v and c) ----
    {
      int col = wv * 16 + nl;
      bf16x8 a0 = *(const bf16x8*)(lds + LD_YBF + lane * 16);
      bf16x8 a1 = *(const bf16x8*)(lds + LD_YBF + 1024 + lane * 16);
      f32x4 av = {0.f, 0.f, 0.f, 0.f}, ac = {0.f, 0.f, 0.f, 0.f};
      av = __builtin_amdgcn_mfma_f32_16x16x32_bf16(
          a0, *(const bf16x8*)(lds + LD_WV0 + wv * 2048 + lane * 16), av, 0, 0, 0);
      av = __builtin_amdgcn_mfma_f32_16x16x32_bf16(
          a1, *(const bf16x8*)(lds + LD_WV0 + wv * 2048 + 1024 + lane * 16), av, 0, 0, 0);
      ac = __builtin_amdgcn_mfma_f32_16x16x32_bf16(
          a0, *(const bf16x8*)(lds + LD_WC0 + wv * 2048 + lane * 16), ac, 0, 0, 0);
      ac = __builtin_amdgcn_mfma_f32_16x16x32_bf16(
          a1, *(const bf16x8*)(lds + LD_WC0 + wv * 2048 + 1024 + lane * 16), ac, 0, 0, 0);
      float bv = ((float*)(lds + LD_BEV))[col];
      float bc = ((float*)(lds + LD_BEC))[col];
#pragma unroll
      for (int r = 0; r < 4; r++) {
        write_act(lds + LD_H1V, quad * 4 + r, col, f2bf(lipswish(av[r] + bv)));
        write_act(lds + LD_H1C, quad * 4 + r, col, f2bf(lipswish(ac[r] + bc)));
      }
    }
    __syncthreads();   // B1
    // ---- L2 ----
    {
      int col = wv * 16 + nl;
      f32x4 av = gemm_tile<4>(lds + LD_H1V, lds + LD_WV1 + wv * 4096, lane);
      f32x4 ac = gemm_tile<4>(lds + LD_H1C, lds + LD_WC1 + wv * 4096, lane);
      float bv = ((float*)(lds + LD_BV1))[col];
      float bc = ((float*)(lds + LD_BC1))[col];
#pragma unroll
      for (int r = 0; r < 4; r++) {
        write_act(lds + LD_H2V, quad * 4 + r, col, f2bf(lipswish(av[r] + bv)));
        write_act(lds + LD_H2C, quad * 4 + r, col, f2bf(lipswish(ac[r] + bc)));
      }
    }
    __syncthreads();   // B2
    // ---- L3: drift (waves 0-3) + diffusion (all waves) ----
    if (wv < 4) {
      f32x4 acc = {0.f, 0.f, 0.f, 0.f};
#pragma unroll
      for (int k = 0; k < 4; k++) {
        bf16x8 a = *(const bf16x8*)(lds + LD_H2V + k * 1024 + lane * 16);
        acc = __builtin_amdgcn_mfma_f32_16x16x32_bf16(a, vf[k], acc, 0, 0, 0);
      }
      int col = wv * 16 + nl;
      float bias = ((float*)(lds + LD_BV2))[col];
      float sv   = ((float*)(lds + LD_SV))[col];
#pragma unroll
      for (int r = 0; r < 4; r++)
        ((float*)(lds + LD_DB))[(quad * 4 + r) * 68 + col] = sv * tanh_fast(acc[r] + bias);
    }
    {
      bf16x8 a[4];
#pragma unroll
      for (int k = 0; k < 4; k++)
        a[k] = *(const bf16x8*)(lds + LD_H2C + k * 1024 + lane * 16);
      float bmr0[4], bmr1[4];
#pragma unroll
      for (int r = 0; r < 4; r++) {
        bmr0[r] = ((float*)(lds + LD_BM))[(quad * 4 + r) * 33 + nl];
        bmr1[r] = ((float*)(lds + LD_BM))[(quad * 4 + r) * 33 + 16 + nl];
      }
      float ps[4] = {0.f, 0.f, 0.f, 0.f};
#pragma unroll
      for (int tt = 0; tt < 16; tt++) {
        f32x4 acc = {0.f, 0.f, 0.f, 0.f};
        if (tt < 4) {
#pragma unroll
          for (int k = 0; k < 4; k++)
            acc = __builtin_amdgcn_mfma_f32_16x16x32_bf16(a[k], wf[tt][k], acc, 0, 0, 0);
        } else {
          int sl = (tt - 4) & 3;
#pragma unroll
          for (int k = 0; k < 4; k++)
            acc = __builtin_amdgcn_mfma_f32_16x16x32_bf16(a[k], rng[sl][k], acc, 0, 0, 0);
          if (tt + 4 <= 15) {
#pragma unroll
            for (int k = 0; k < 4; k++)
              rng[sl][k] = *(const bf16x8*)(wc2 + (tt + 4) * 4096 + k * 1024 + lane * 16);
          }
        }
        int ntA = wv * 16 + tt;
        uint32_t bsc = ((const uint32_t*)(lds + LD_BSC))[ntA * 16 + nl];
        float bc2v = bf2f((short)(bsc & 0xffffu));
        float scv  = bf2f((short)(bsc >> 16));
        int half = tt & 1;
#pragma unroll
        for (int r = 0; r < 4; r++) {
          float bmv = half ? bmr1[r] : bmr0[r];
          float p = tanh_fast(acc[r] + bc2v) * scv * bmv;
          ps[r] = half ? (ps[r] + p) : p;
        }
        if (half) {
#pragma unroll
          for (int r = 0; r < 4; r++) ps[r] = red16(ps[r]);
          if (nl < 4) {
            int row = quad * 4 + nl;
            float s = (nl == 0) ? ps[0] : (nl == 1) ? ps[1] : (nl == 2) ? ps[2] : ps[3];
            float* yp = (float*)(lds + LD_Y) + row * 68 + (ntA >> 1);
            *yp += s;   // exclusive h-range per wave: race-free
          }
        }
      }
    }
    __syncthreads();   // B3
    // ---- M: vnew = Y(+diff) + DB; rebuild YBF; stage bm/biases (regs) ----
    if (tid < 256) {
      int row = tid >> 4, kb = (tid & 15) * 4;
      f32x4 yv = *(const f32x4*)(lds + LD_Y  + (row * 68 + kb) * 4);
      f32x4 db = *(const f32x4*)(lds + LD_DB + (row * 68 + kb) * 4);
      f32x4 vn = yv + db;
      *(f32x4*)(lds + LD_Y + (row * 68 + kb) * 4) = vn;
      uint32_t p0 = (uint32_t)(uint16_t)f2bf(vn[0]) | ((uint32_t)(uint16_t)f2bf(vn[1]) << 16);
      uint32_t p1 = (uint32_t)(uint16_t)f2bf(vn[2]) | ((uint32_t)(uint16_t)f2bf(vn[3]) << 16);
      uint64_t p64 = (uint64_t)p0 | ((uint64_t)p1 << 32);
      int addr = LD_YBF + ((kb >> 5) << 10) + (row + ((kb >> 3) & 3) * 16) * 16 + ((kb & 7) << 1);
      *(uint64_t*)(lds + addr) = p64;
    } else if (step + 1 < 64) {
      int j = tid - 256; float v = bbq + (ts0 + (float)(step + 1)) * tvq;
      if (j < 128) ((float*)(lds + LD_BEV))[j] = v;
      else         ((float*)(lds + LD_BEC))[j - 128] = v;
    }
    if (step + 1 < 64)
      ((float*)(lds + LD_BM))[(tid >> 5) * 33 + (tid & 31)] = bm_next;
    __syncthreads();   // B4
    // ---- readout (waves 0-1; waves 2-7 run ahead into next L1) ----
    if (tid < 128) {
      int row = tid >> 3, dd = tid & 7;
      const float* yr = (const float*)(lds + LD_Y) + row * 68;
      const float* wr = (const float*)(lds + LD_WR) + dd * 68;
      float s = ((float*)(lds + LD_BR))[dd];
#pragma unroll
      for (int k = 0; k < 64; k++) s = fmaf(yr[k], wr[k], s);
      out[(size_t)(b0 + row) * 512 + step * 8 + dd] = s;
    }
  }
}

extern "C" void kernel_launch(void* const* d_in, const int* in_sizes, int n_in,
                              void* d_out, int out_size, void* d_ws, size_t ws_size,
                              hipStream_t stream) {
  (void)in_sizes; (void)n_in; (void)out_size; (void)ws_size;
  const float* ts         = (const float*)d_in[0];
  const float* init_noise = (const float*)d_in[1];
  const float* bm         = (const float*)d_in[2];
  const float* Wi0 = (const float*)d_in[3];
  const float* bi0 = (const float*)d_in[4];
  const float* Wi1 = (const float*)d_in[5];
  const float* bi1 = (const float*)d_in[6];
  const float* Wi2 = (const float*)d_in[7];
  const float* bi2 = (const float*)d_in[8];
  const float* scale_v = (const float*)d_in[9];
  const float* Wv0 = (const float*)d_in[10];
  const float* bv0 = (const float*)d_in[11];
  const float* Wv1 = (const float*)d_in[12];
  const float* bv1 = (const float*)d_in[13];
  const float* Wv2 = (const float*)d_in[14];
  const float* bv2 = (const float*)d_in[15];
  const float* scale_c = (const float*)d_in[16];
  const float* Wc0 = (const float*)d_in[17];
  const float* bc0 = (const float*)d_in[18];
  const float* Wc1 = (const float*)d_in[19];
  const float* bc1 = (const float*)d_in[20];
  const float* Wc2 = (const float*)d_in[21];
  const float* bc2 = (const float*)d_in[22];
  const float* Wr  = (const float*)d_in[23];
  const float* br  = (const float*)d_in[24];
  char*  ws  = (char*)d_ws;
  float* out = (float*)d_out;

  hipFuncSetAttribute((const void*)sde_kernel,
                      hipFuncAttributeMaxDynamicSharedMemorySize, LDS_TOTAL);

  prep_kernel<<<171, 256, 0, stream>>>(Wi0, Wi1, Wi2, Wv0, Wv1, Wv2, Wc0, Wc1, Wc2, ws);
  sde_kernel<<<NWG, 512, LDS_TOTAL, stream>>>(
      ts, init_noise, bm, bi0, bi1, bi2, bv0, bv1, bv2, scale_v,
      bc0, bc1, bc2, scale_c, Wr, br, ws, out);
}